// Round 1
// baseline (491.730 us; speedup 1.0000x reference)
//
#include <hip/hip_runtime.h>
#include <stdint.h>

#define MDIM 4096
#define KDIM 4096
#define NDIM 11008
#define KP   (KDIM/8)   // 512 packed int32 per N-row

typedef float  f32x4  __attribute__((ext_vector_type(4)));
typedef __bf16 bf16x8 __attribute__((ext_vector_type(8)));
typedef unsigned short u16x8 __attribute__((ext_vector_type(8)));

// RNE f32 -> bf16 bits (matches jax astype(bf16) for non-NaN inputs)
__device__ __forceinline__ unsigned short f2bf(float f) {
  uint32_t u = __builtin_bit_cast(uint32_t, f);
  u += 0x7FFFu + ((u >> 16) & 1u);
  return (unsigned short)(u >> 16);
}
__device__ __forceinline__ float bf2f(unsigned short h) {
  return __builtin_bit_cast(float, (uint32_t)h << 16);
}
__device__ __forceinline__ float bf16r(float f) { return bf2f(f2bf(f)); }

// async global -> LDS, 16B per lane, wave-uniform LDS base + lane*16
__device__ __forceinline__ void lds16(const void* g, void* l) {
  __builtin_amdgcn_global_load_lds(
      (const __attribute__((address_space(1))) unsigned int*)g,
      (__attribute__((address_space(3))) unsigned int*)l, 16, 0, 0);
}

// ---------------- pre-pass 1: dequant packed int4 -> bf16 W[N][K] -----------
// one thread per int32 word; grid*block == N*KP exactly (22016*256)
__global__ __launch_bounds__(256) void dequant_w_kernel(
    const uint32_t* __restrict__ wq, const float* __restrict__ scales,
    const float* __restrict__ zeros, u16x8* __restrict__ Wbf) {
  int idx = blockIdx.x * 256 + threadIdx.x;      // [0, N*KP)
  int n = idx >> 9;                              // idx / 512
  float s = bf16r(scales[n]);
  float z = bf16r(zeros[n]);
  uint32_t w = wq[idx];
  u16x8 v;
#pragma unroll
  for (int j = 0; j < 8; ++j) {
    float qf = (float)((w >> (4 * j)) & 0xF);
    float t  = bf16r(qf * s);                    // bf16 mul rounding
    v[j] = f2bf(t + z);                          // bf16 add rounding
  }
  Wbf[idx] = v;                                  // 16B store
}

// ---------------- pre-pass 2: x f32 -> bf16 ---------------------------------
// one thread per 8 floats; grid*block == M*K/8 exactly (8192*256)
__global__ __launch_bounds__(256) void convert_x_kernel(
    const float4* __restrict__ x, u16x8* __restrict__ Xbf) {
  int idx = blockIdx.x * 256 + threadIdx.x;
  float4 a = x[2 * idx], b = x[2 * idx + 1];
  u16x8 v;
  v[0] = f2bf(a.x); v[1] = f2bf(a.y); v[2] = f2bf(a.z); v[3] = f2bf(a.w);
  v[4] = f2bf(b.x); v[5] = f2bf(b.y); v[6] = f2bf(b.z); v[7] = f2bf(b.w);
  Xbf[idx] = v;
}

// ---------------- GEMM: 128x128 tile, BK=64, 4 waves (2x2), 16x16x32 bf16 ---
// FUSED=false: A,B are pre-converted bf16 in ws, staged via global_load_lds.
// FUSED=true : A converted f32->bf16 on the fly, B dequantized on the fly
//              (reg-staged ds_write_b128), same MFMA inner loop.
template <bool FUSED>
__global__ __launch_bounds__(256, 3) void gemm_kernel(
    const float* __restrict__ x, const uint32_t* __restrict__ wq,
    const float* __restrict__ scales, const float* __restrict__ zeros,
    const unsigned short* __restrict__ Abf, const unsigned short* __restrict__ Bbf,
    const float* __restrict__ bias, float* __restrict__ out) {
  __shared__ __align__(16) char smem[2 * 128 * 64 * 2];  // As 16KB | Bs 16KB
  char* As = smem;
  char* Bs = smem + 16384;

  const int tid  = threadIdx.x;
  const int lane = tid & 63;
  const int wave = tid >> 6;
  const int wm = wave >> 1, wn = wave & 1;

  // XCD-aware swizzle; nwg = 32*86 = 2752, divisible by 8. n-tile fastest so
  // consecutive blocks on one XCD share the same A panel (1MB bf16, L2-fits).
  const int b   = blockIdx.x;
  const int swz = (b & 7) * 344 + (b >> 3);
  const int mt  = swz / 86;
  const int nt  = swz - mt * 86;
  const int bm0 = mt * 128, bn0 = nt * 128;

  f32x4 acc[4][4];
#pragma unroll
  for (int i = 0; i < 4; ++i)
#pragma unroll
    for (int j = 0; j < 4; ++j) acc[i][j] = (f32x4){0.f, 0.f, 0.f, 0.f};

  // fragment read bases (bytes): row*128 + kgroup*16
  const int base_a = ((wm * 64 + (lane & 15)) << 7) + ((lane >> 4) << 4);
  const int base_b = ((wn * 64 + (lane & 15)) << 7) + ((lane >> 4) << 4);

  // staging lane assignments
  const int rA = lane >> 3, cA = lane & 7;  // !FUSED: row-in-chunk, 16B col

  float sv[4], zv[4];
  if constexpr (FUSED) {
#pragma unroll
    for (int it = 0; it < 4; ++it) {
      int r = bn0 + it * 32 + (tid >> 3);
      sv[it] = bf16r(scales[r]);
      zv[it] = bf16r(zeros[r]);
    }
  }

  for (int kt = 0; kt < KDIM / 64; ++kt) {
    const int k0 = kt * 64;
    __syncthreads();  // previous tile fully consumed
    if constexpr (!FUSED) {
      // 16 chunks of 1KB per tile; wave stages chunks [wave*4, wave*4+4)
#pragma unroll
      for (int c = 0; c < 4; ++c) {
        int chunk = wave * 4 + c;
        int row = chunk * 8 + rA;
        lds16(Abf + (size_t)(bm0 + row) * KDIM + k0 + cA * 8, As + chunk * 1024);
        lds16(Bbf + (size_t)(bn0 + row) * KDIM + k0 + cA * 8, Bs + chunk * 1024);
      }
    } else {
      // A: f32 -> bf16, 1024 chunks of 8 floats, 4 per thread
#pragma unroll
      for (int it = 0; it < 4; ++it) {
        int ch = it * 256 + tid;
        int row = ch >> 3, c8 = ch & 7;
        const float* src = x + (size_t)(bm0 + row) * KDIM + k0 + c8 * 8;
        float4 f0 = *(const float4*)src;
        float4 f1 = *(const float4*)(src + 4);
        u16x8 v;
        v[0] = f2bf(f0.x); v[1] = f2bf(f0.y); v[2] = f2bf(f0.z); v[3] = f2bf(f0.w);
        v[4] = f2bf(f1.x); v[5] = f2bf(f1.y); v[6] = f2bf(f1.z); v[7] = f2bf(f1.w);
        *(u16x8*)(As + row * 128 + c8 * 16) = v;
      }
      // B: dequant 1024 int32 words, 4 per thread (rows fixed per thread)
#pragma unroll
      for (int it = 0; it < 4; ++it) {
        int ch = it * 256 + tid;
        int row = ch >> 3, kp = ch & 7;
        uint32_t w = wq[(size_t)(bn0 + row) * KP + kt * 8 + kp];
        float s = sv[it], z = zv[it];
        u16x8 v;
#pragma unroll
        for (int j = 0; j < 8; ++j) {
          float qf = (float)((w >> (4 * j)) & 0xF);
          float t  = bf16r(qf * s);
          v[j] = f2bf(t + z);
        }
        *(u16x8*)(Bs + row * 128 + kp * 16) = v;
      }
    }
    __syncthreads();  // tile ready (drains vmcnt/lgkmcnt)

#pragma unroll
    for (int ks = 0; ks < 2; ++ks) {
      bf16x8 af[4], bf[4];
#pragma unroll
      for (int i = 0; i < 4; ++i)
        af[i] = *(const bf16x8*)(As + base_a + i * 2048 + ks * 64);
#pragma unroll
      for (int j = 0; j < 4; ++j)
        bf[j] = *(const bf16x8*)(Bs + base_b + j * 2048 + ks * 64);
#pragma unroll
      for (int i = 0; i < 4; ++i)
#pragma unroll
        for (int j = 0; j < 4; ++j)
          acc[i][j] = __builtin_amdgcn_mfma_f32_16x16x32_bf16(af[i], bf[j],
                                                              acc[i][j], 0, 0, 0);
    }
  }

  // epilogue: C/D layout col=lane&15 (n), row=(lane>>4)*4+reg (m)
  const int colbase = bn0 + wn * 64 + (lane & 15);
  const int rowbase = bm0 + wm * 64 + ((lane >> 4) << 2);
  float bv[4];
#pragma unroll
  for (int j = 0; j < 4; ++j) bv[j] = bias[colbase + j * 16];
#pragma unroll
  for (int i = 0; i < 4; ++i) {
#pragma unroll
    for (int j = 0; j < 4; ++j) {
      size_t base = (size_t)(rowbase + i * 16) * NDIM + colbase + j * 16;
#pragma unroll
      for (int r = 0; r < 4; ++r)
        out[base + (size_t)r * NDIM] = acc[i][j][r] + bv[j];
    }
  }
}

extern "C" void kernel_launch(void* const* d_in, const int* in_sizes, int n_in,
                              void* d_out, int out_size, void* d_ws, size_t ws_size,
                              hipStream_t stream) {
  const float*    x      = (const float*)d_in[0];
  const uint32_t* wq     = (const uint32_t*)d_in[1];
  const float*    scales = (const float*)d_in[2];
  const float*    zeros  = (const float*)d_in[3];
  const float*    bias   = (const float*)d_in[4];
  float*          out    = (float*)d_out;

  const size_t needW = (size_t)NDIM * KDIM * 2;  // 90,177,536 B
  const size_t needX = (size_t)MDIM * KDIM * 2;  // 33,554,432 B

  if (ws_size >= needW + needX) {
    unsigned short* Wbf = (unsigned short*)d_ws;
    unsigned short* Xbf = (unsigned short*)((char*)d_ws + needW);
    dequant_w_kernel<<<(NDIM * KP) / 256, 256, 0, stream>>>(wq, scales, zeros,
                                                            (u16x8*)Wbf);
    convert_x_kernel<<<(MDIM * KDIM / 8) / 256, 256, 0, stream>>>(
        (const float4*)x, (u16x8*)Xbf);
    gemm_kernel<false><<<2752, 256, 0, stream>>>(x, wq, scales, zeros, Xbf, Wbf,
                                                 bias, out);
  } else {
    gemm_kernel<true><<<2752, 256, 0, stream>>>(x, wq, scales, zeros, nullptr,
                                                nullptr, bias, out);
  }
}

// Round 2
// 422.886 us; speedup vs baseline: 1.1628x; 1.1628x over previous
//
#include <hip/hip_runtime.h>
#include <stdint.h>

#define MDIM 4096
#define KDIM 4096
#define NDIM 11008
#define KP   (KDIM/8)   // 512 packed int32 per N-row
#define NKT  (KDIM/64)  // 64 K-steps of BK=64

typedef float  f32x4  __attribute__((ext_vector_type(4)));
typedef __bf16 bf16x8 __attribute__((ext_vector_type(8)));
typedef unsigned short u16x8 __attribute__((ext_vector_type(8)));

// RNE f32 -> bf16 bits (matches jax astype(bf16) for non-NaN inputs)
__device__ __forceinline__ unsigned short f2bf(float f) {
  uint32_t u = __builtin_bit_cast(uint32_t, f);
  u += 0x7FFFu + ((u >> 16) & 1u);
  return (unsigned short)(u >> 16);
}
__device__ __forceinline__ float bf2f(unsigned short h) {
  return __builtin_bit_cast(float, (uint32_t)h << 16);
}
__device__ __forceinline__ float bf16r(float f) { return bf2f(f2bf(f)); }

// async global -> LDS, 16B per lane, wave-uniform LDS base + lane*16
__device__ __forceinline__ void lds16(const void* g, void* l) {
  __builtin_amdgcn_global_load_lds(
      (const __attribute__((address_space(1))) unsigned int*)g,
      (__attribute__((address_space(3))) unsigned int*)l, 16, 0, 0);
}

// ---------------- pre-pass 1: dequant packed int4 -> bf16 W[N][K] -----------
__global__ __launch_bounds__(256) void dequant_w_kernel(
    const uint32_t* __restrict__ wq, const float* __restrict__ scales,
    const float* __restrict__ zeros, u16x8* __restrict__ Wbf) {
  int idx = blockIdx.x * 256 + threadIdx.x;      // [0, N*KP)
  int n = idx >> 9;                              // idx / 512
  float s = bf16r(scales[n]);
  float z = bf16r(zeros[n]);
  uint32_t w = wq[idx];
  u16x8 v;
#pragma unroll
  for (int j = 0; j < 8; ++j) {
    float qf = (float)((w >> (4 * j)) & 0xF);
    float t  = bf16r(qf * s);                    // bf16 mul rounding
    v[j] = f2bf(t + z);                          // bf16 add rounding
  }
  Wbf[idx] = v;
}

// ---------------- pre-pass 2: x f32 -> bf16 ---------------------------------
__global__ __launch_bounds__(256) void convert_x_kernel(
    const float4* __restrict__ x, u16x8* __restrict__ Xbf) {
  int idx = blockIdx.x * 256 + threadIdx.x;
  float4 a = x[2 * idx], b = x[2 * idx + 1];
  u16x8 v;
  v[0] = f2bf(a.x); v[1] = f2bf(a.y); v[2] = f2bf(a.z); v[3] = f2bf(a.w);
  v[4] = f2bf(b.x); v[5] = f2bf(b.y); v[6] = f2bf(b.z); v[7] = f2bf(b.w);
  Xbf[idx] = v;
}

// ---------------- main GEMM: 256x256 tile, BK=64, 8 waves (2M x 4N) ---------
// Double-buffered K-tiles (2 x 64KB LDS), counted vmcnt(8) (never 0 in loop),
// st_16x32 LDS swizzle via pre-permuted global source + swizzled ds_read,
// setprio around MFMA clusters, XCD-bijective block swizzle (688 % 8 == 0).
//
// LDS map per buffer (64KB): A: 32 subtiles of 1KB (subtile = 16 rows x 32 k,
// row-major 64B rows, byte ^= ((byte>>9)&1)<<5); then B likewise at +32KB.
// Subtile index = (row>>4)*2 + (k>>5).
__global__ __launch_bounds__(512, 2) void gemm256_kernel(
    const unsigned short* __restrict__ Abf,
    const unsigned short* __restrict__ Bbf,
    const float* __restrict__ bias, float* __restrict__ out) {
  __shared__ __align__(16) char smem[131072];

  const int tid  = threadIdx.x;
  const int lane = tid & 63;
  const int wave = tid >> 6;     // 0..7
  const int wm   = wave >> 2;    // 0..1 : M half (128 rows)
  const int wn   = wave & 3;     // 0..3 : N quarter (64 cols)

  // XCD-aware bijective swizzle: 688 = 8 * 86 blocks; n-tile fastest within
  // a chunk so blocks on one XCD share A panels (2MB, L2-fits).
  const int b   = blockIdx.x;
  const int swz = (b & 7) * 86 + (b >> 3);
  const int mt  = swz / 43;
  const int nt  = swz - mt * 43;
  const int bm0 = mt * 256, bn0 = nt * 256;

  // ---- staging geometry (inverse st_16x32 permutation on the SOURCE) ----
  // lane l writes LDS bytes [l*16, l*16+16) of one 1KB subtile; the element
  // the swizzled reader expects there sits at linear offset (l>=32 ? l^2 : l)*16.
  const int lp   = (lane >= 32) ? (lane ^ 2) : lane;
  const int srow = lp >> 2;        // 0..15
  const int scol = (lp & 3) << 3;  // 0,8,16,24 (bf16 elems)
  // wave stages rows [wave*32, wave*32+32), both 32-wide k-blocks (4 subtiles ea.)
  const unsigned short* aR = Abf + (size_t)(bm0 + wave * 32 + srow) * KDIM + scol;
  const unsigned short* bR = Bbf + (size_t)(bn0 + wave * 32 + srow) * KDIM + scol;

  // ---- fragment-read per-lane offset (st_16x32 swizzled) ----
  // linear: (lane&15)*64 + (lane>>4)*16 ; swizzle flips bit5 when row bit3 set
  int rd = ((lane & 15) << 6) | ((lane >> 4) << 4);
  rd ^= ((lane >> 3) & 1) << 5;

  f32x4 acc[8][4];
#pragma unroll
  for (int i = 0; i < 8; ++i)
#pragma unroll
    for (int j = 0; j < 4; ++j) acc[i][j] = (f32x4){0.f, 0.f, 0.f, 0.f};

#define STAGE(KT, BUF)                                                        \
  do {                                                                        \
    const int k0_ = (KT) * 64;                                                \
    char* la_ = smem + (BUF) * 65536 + wave * 4096;                           \
    char* lb_ = la_ + 32768;                                                  \
    lds16(aR + k0_,                          la_);                            \
    lds16(aR + k0_ + 32,                     la_ + 1024);                     \
    lds16(aR + (size_t)16 * KDIM + k0_,      la_ + 2048);                     \
    lds16(aR + (size_t)16 * KDIM + k0_ + 32, la_ + 3072);                     \
    lds16(bR + k0_,                          lb_);                            \
    lds16(bR + k0_ + 32,                     lb_ + 1024);                     \
    lds16(bR + (size_t)16 * KDIM + k0_,      lb_ + 2048);                     \
    lds16(bR + (size_t)16 * KDIM + k0_ + 32, lb_ + 3072);                     \
  } while (0)

  // prologue: fill both buffers; wait only for K-tile 0 (K-tile 1 in flight)
  STAGE(0, 0);
  STAGE(1, 1);
  asm volatile("s_waitcnt vmcnt(8)" ::: "memory");
  __builtin_amdgcn_s_barrier();
  __builtin_amdgcn_sched_barrier(0);

  const char* aLds0 = smem + wm * 16384;          // wm*8 subtiles * 2KB
  const char* bLds0 = smem + 32768 + wn * 8192;   // wn*4 subtiles * 2KB

  for (int kt = 0; kt < NKT; ++kt) {
    const int cur = kt & 1;
    const char* ab = aLds0 + cur * 65536 + rd;
    const char* bb = bLds0 + cur * 65536 + rd;

    bf16x8 Bf[4][2];  // B fragments held across both phases
#pragma unroll
    for (int nf = 0; nf < 4; ++nf)
#pragma unroll
      for (int ks = 0; ks < 2; ++ks)
        Bf[nf][ks] = *(const bf16x8*)(bb + nf * 2048 + ks * 1024);

    bf16x8 Af[4][2];
    // ---- phase A: m-frags 0..3 ----
#pragma unroll
    for (int mf = 0; mf < 4; ++mf)
#pragma unroll
      for (int ks = 0; ks < 2; ++ks)
        Af[mf][ks] = *(const bf16x8*)(ab + mf * 2048 + ks * 1024);
    __builtin_amdgcn_s_setprio(1);
#pragma unroll
    for (int mf = 0; mf < 4; ++mf)
#pragma unroll
      for (int nf = 0; nf < 4; ++nf)
#pragma unroll
        for (int ks = 0; ks < 2; ++ks)
          acc[mf][nf] = __builtin_amdgcn_mfma_f32_16x16x32_bf16(
              Af[mf][ks], Bf[nf][ks], acc[mf][nf], 0, 0, 0);
    __builtin_amdgcn_s_setprio(0);
    // ---- phase B: m-frags 4..7 ----
#pragma unroll
    for (int mf = 0; mf < 4; ++mf)
#pragma unroll
      for (int ks = 0; ks < 2; ++ks)
        Af[mf][ks] = *(const bf16x8*)(ab + (4 + mf) * 2048 + ks * 1024);
    __builtin_amdgcn_s_setprio(1);
#pragma unroll
    for (int mf = 0; mf < 4; ++mf)
#pragma unroll
      for (int nf = 0; nf < 4; ++nf)
#pragma unroll
        for (int ks = 0; ks < 2; ++ks)
          acc[4 + mf][nf] = __builtin_amdgcn_mfma_f32_16x16x32_bf16(
              Af[mf][ks], Bf[nf][ks], acc[4 + mf][nf], 0, 0, 0);
    __builtin_amdgcn_s_setprio(0);

    __builtin_amdgcn_s_barrier();      // all waves done reading buf[cur]
    __builtin_amdgcn_sched_barrier(0);
    if (kt + 2 < NKT) {
      STAGE(kt + 2, cur);              // overwrite now-dead buffer
      // kt+1 landed (its 8 loads are the oldest); kt+2's 8 stay in flight
      asm volatile("s_waitcnt vmcnt(8)" ::: "memory");
      __builtin_amdgcn_s_barrier();
      __builtin_amdgcn_sched_barrier(0);
    } else if (kt + 1 < NKT) {
      asm volatile("s_waitcnt vmcnt(0)" ::: "memory");  // drain once, at the end
      __builtin_amdgcn_s_barrier();
      __builtin_amdgcn_sched_barrier(0);
    }
  }
#undef STAGE

  // epilogue: C/D layout col=lane&15 (n), row=(lane>>4)*4+reg (m)
  const int colbase = bn0 + wn * 64 + (lane & 15);
  const int rowbase = bm0 + wm * 128 + ((lane >> 4) << 2);
  float bv[4];
#pragma unroll
  for (int nf = 0; nf < 4; ++nf) bv[nf] = bias[colbase + nf * 16];
#pragma unroll
  for (int mf = 0; mf < 8; ++mf)
#pragma unroll
    for (int nf = 0; nf < 4; ++nf) {
      size_t base = (size_t)(rowbase + mf * 16) * NDIM + colbase + nf * 16;
#pragma unroll
      for (int r = 0; r < 4; ++r)
        out[base + (size_t)r * NDIM] = acc[mf][nf][r] + bv[nf];
    }
}

// ---------------- fallback fused 128x128 kernel (ws too small) --------------
__global__ __launch_bounds__(256, 3) void gemm_fused_kernel(
    const float* __restrict__ x, const uint32_t* __restrict__ wq,
    const float* __restrict__ scales, const float* __restrict__ zeros,
    const float* __restrict__ bias, float* __restrict__ out) {
  __shared__ __align__(16) char smem[2 * 128 * 64 * 2];
  char* As = smem;
  char* Bs = smem + 16384;

  const int tid  = threadIdx.x;
  const int lane = tid & 63;
  const int wave = tid >> 6;
  const int wm = wave >> 1, wn = wave & 1;

  const int b   = blockIdx.x;
  const int swz = (b & 7) * 344 + (b >> 3);
  const int mt  = swz / 86;
  const int nt  = swz - mt * 86;
  const int bm0 = mt * 128, bn0 = nt * 128;

  f32x4 acc[4][4];
#pragma unroll
  for (int i = 0; i < 4; ++i)
#pragma unroll
    for (int j = 0; j < 4; ++j) acc[i][j] = (f32x4){0.f, 0.f, 0.f, 0.f};

  const int base_a = ((wm * 64 + (lane & 15)) << 7) + ((lane >> 4) << 4);
  const int base_b = ((wn * 64 + (lane & 15)) << 7) + ((lane >> 4) << 4);

  float sv[4], zv[4];
#pragma unroll
  for (int it = 0; it < 4; ++it) {
    int r = bn0 + it * 32 + (tid >> 3);
    sv[it] = bf16r(scales[r]);
    zv[it] = bf16r(zeros[r]);
  }

  for (int kt = 0; kt < KDIM / 64; ++kt) {
    const int k0 = kt * 64;
    __syncthreads();
#pragma unroll
    for (int it = 0; it < 4; ++it) {
      int ch = it * 256 + tid;
      int row = ch >> 3, c8 = ch & 7;
      const float* src = x + (size_t)(bm0 + row) * KDIM + k0 + c8 * 8;
      float4 f0 = *(const float4*)src;
      float4 f1 = *(const float4*)(src + 4);
      u16x8 v;
      v[0] = f2bf(f0.x); v[1] = f2bf(f0.y); v[2] = f2bf(f0.z); v[3] = f2bf(f0.w);
      v[4] = f2bf(f1.x); v[5] = f2bf(f1.y); v[6] = f2bf(f1.z); v[7] = f2bf(f1.w);
      *(u16x8*)(As + row * 128 + c8 * 16) = v;
    }
#pragma unroll
    for (int it = 0; it < 4; ++it) {
      int ch = it * 256 + tid;
      int row = ch >> 3, kp = ch & 7;
      uint32_t w = wq[(size_t)(bn0 + row) * KP + kt * 8 + kp];
      float s = sv[it], z = zv[it];
      u16x8 v;
#pragma unroll
      for (int j = 0; j < 8; ++j) {
        float qf = (float)((w >> (4 * j)) & 0xF);
        float t  = bf16r(qf * s);
        v[j] = f2bf(t + z);
      }
      *(u16x8*)(Bs + row * 128 + kp * 16) = v;
    }
    __syncthreads();
#pragma unroll
    for (int ks = 0; ks < 2; ++ks) {
      bf16x8 af[4], bf[4];
#pragma unroll
      for (int i = 0; i < 4; ++i)
        af[i] = *(const bf16x8*)(As + base_a + i * 2048 + ks * 64);
#pragma unroll
      for (int j = 0; j < 4; ++j)
        bf[j] = *(const bf16x8*)(Bs + base_b + j * 2048 + ks * 64);
#pragma unroll
      for (int i = 0; i < 4; ++i)
#pragma unroll
        for (int j = 0; j < 4; ++j)
          acc[i][j] = __builtin_amdgcn_mfma_f32_16x16x32_bf16(af[i], bf[j],
                                                              acc[i][j], 0, 0, 0);
    }
  }

  const int colbase = bn0 + wn * 64 + (lane & 15);
  const int rowbase = bm0 + wm * 64 + ((lane >> 4) << 2);
  float bv[4];
#pragma unroll
  for (int j = 0; j < 4; ++j) bv[j] = bias[colbase + j * 16];
#pragma unroll
  for (int i = 0; i < 4; ++i) {
#pragma unroll
    for (int j = 0; j < 4; ++j) {
      size_t base = (size_t)(rowbase + i * 16) * NDIM + colbase + j * 16;
#pragma unroll
      for (int r = 0; r < 4; ++r)
        out[base + (size_t)r * NDIM] = acc[i][j][r] + bv[j];
    }
  }
}

extern "C" void kernel_launch(void* const* d_in, const int* in_sizes, int n_in,
                              void* d_out, int out_size, void* d_ws, size_t ws_size,
                              hipStream_t stream) {
  const float*    x      = (const float*)d_in[0];
  const uint32_t* wq     = (const uint32_t*)d_in[1];
  const float*    scales = (const float*)d_in[2];
  const float*    zeros  = (const float*)d_in[3];
  const float*    bias   = (const float*)d_in[4];
  float*          out    = (float*)d_out;

  const size_t needW = (size_t)NDIM * KDIM * 2;  // 90,177,536 B
  const size_t needX = (size_t)MDIM * KDIM * 2;  // 33,554,432 B

  if (ws_size >= needW + needX) {
    unsigned short* Wbf = (unsigned short*)d_ws;
    unsigned short* Xbf = (unsigned short*)((char*)d_ws + needW);
    dequant_w_kernel<<<(NDIM * KP) / 256, 256, 0, stream>>>(wq, scales, zeros,
                                                            (u16x8*)Wbf);
    convert_x_kernel<<<(MDIM * KDIM / 8) / 256, 256, 0, stream>>>(
        (const float4*)x, (u16x8*)Xbf);
    gemm256_kernel<<<688, 512, 0, stream>>>(Xbf, Wbf, bias, out);
  } else {
    gemm_fused_kernel<<<2752, 256, 0, stream>>>(x, wq, scales, zeros, bias, out);
  }
}

// Round 3
// 385.489 us; speedup vs baseline: 1.2756x; 1.0970x over previous
//
#include <hip/hip_runtime.h>
#include <stdint.h>

#define MDIM 4096
#define KDIM 4096
#define NDIM 11008
#define KP   (KDIM/8)   // 512 packed int32 per N-row
#define NKT  (KDIM/64)  // 64 K-steps of BK=64

typedef float  f32x4  __attribute__((ext_vector_type(4)));
typedef __bf16 bf16x8 __attribute__((ext_vector_type(8)));
typedef unsigned short u16x8 __attribute__((ext_vector_type(8)));

// RNE f32 -> bf16 bits (matches jax astype(bf16) for non-NaN inputs)
__device__ __forceinline__ unsigned short f2bf(float f) {
  uint32_t u = __builtin_bit_cast(uint32_t, f);
  u += 0x7FFFu + ((u >> 16) & 1u);
  return (unsigned short)(u >> 16);
}
__device__ __forceinline__ float bf2f(unsigned short h) {
  return __builtin_bit_cast(float, (uint32_t)h << 16);
}
__device__ __forceinline__ float bf16r(float f) { return bf2f(f2bf(f)); }

// async global -> LDS, 16B per lane, wave-uniform LDS base + lane*16
__device__ __forceinline__ void lds16(const void* g, void* l) {
  __builtin_amdgcn_global_load_lds(
      (const __attribute__((address_space(1))) unsigned int*)g,
      (__attribute__((address_space(3))) unsigned int*)l, 16, 0, 0);
}

// ---------------- pre-pass 1: dequant packed int4 -> bf16 W[N][K] -----------
__global__ __launch_bounds__(256) void dequant_w_kernel(
    const uint32_t* __restrict__ wq, const float* __restrict__ scales,
    const float* __restrict__ zeros, u16x8* __restrict__ Wbf) {
  int idx = blockIdx.x * 256 + threadIdx.x;      // [0, N*KP)
  int n = idx >> 9;                              // idx / 512
  float s = bf16r(scales[n]);
  float z = bf16r(zeros[n]);
  uint32_t w = wq[idx];
  u16x8 v;
#pragma unroll
  for (int j = 0; j < 8; ++j) {
    float qf = (float)((w >> (4 * j)) & 0xF);
    float t  = bf16r(qf * s);                    // bf16 mul rounding
    v[j] = f2bf(t + z);                          // bf16 add rounding
  }
  Wbf[idx] = v;
}

// ---------------- pre-pass 2: x f32 -> bf16 ---------------------------------
__global__ __launch_bounds__(256) void convert_x_kernel(
    const float4* __restrict__ x, u16x8* __restrict__ Xbf) {
  int idx = blockIdx.x * 256 + threadIdx.x;
  float4 a = x[2 * idx], b = x[2 * idx + 1];
  u16x8 v;
  v[0] = f2bf(a.x); v[1] = f2bf(a.y); v[2] = f2bf(a.z); v[3] = f2bf(a.w);
  v[4] = f2bf(b.x); v[5] = f2bf(b.y); v[6] = f2bf(b.z); v[7] = f2bf(b.w);
  Xbf[idx] = v;
}

// ---------------- main GEMM: 256x256, BK=64, 8 waves, 4-phase/K-tile --------
// K-half ring buffers: A = 4 slots x 16KB (rows 0-255 x 32k), B likewise at
// +64KB. Slot(t,ks) = (2t+ks)&3. Each slot = 16 subtiles (16r x 32k, 1KB) with
// st_16x32 XOR swizzle (pre-permuted global source, swizzled ds_read — proven
// 0-conflict in round 1). Per tile: 4 phases, each {4-8 ds_read_b128 | stage
// one K-half (2 lds16/thread = one subtile/wave per lds16) | barrier | 16 MFMA
// (setprio) | barrier}. vmcnt(8) at p1/p3 = 4 half-tiles in flight, staged 6
// phases ahead of consumption; never drains to 0 until the tail.
__global__ __launch_bounds__(512, 2) void gemm256_kernel(
    const unsigned short* __restrict__ Abf,
    const unsigned short* __restrict__ Bbf,
    const float* __restrict__ bias, float* __restrict__ out) {
  __shared__ __align__(16) char smem[131072];

  const int tid  = threadIdx.x;
  const int lane = tid & 63;
  const int wave = tid >> 6;     // 0..7
  const int wm   = wave >> 2;    // 0..1 : M half (128 rows)
  const int wn   = wave & 3;     // 0..3 : N quarter (64 cols)

  // XCD-aware bijective swizzle: 688 = 8 * 86 blocks.
  const int b   = blockIdx.x;
  const int swz = (b & 7) * 86 + (b >> 3);
  const int mt  = swz / 43;
  const int nt  = swz - mt * 43;
  const int bm0 = mt * 256, bn0 = nt * 256;

  // staging: inverse st_16x32 permutation on the SOURCE (round-1 verified)
  const int lp   = (lane >= 32) ? (lane ^ 2) : lane;
  const int srow = lp >> 2;        // 0..15
  const int scol = (lp & 3) << 3;  // 0,8,16,24 (bf16 elems)
  const unsigned short* aR = Abf + (size_t)(bm0 + wave * 32 + srow) * KDIM + scol;
  const unsigned short* bR = Bbf + (size_t)(bn0 + wave * 32 + srow) * KDIM + scol;

  // swizzled per-lane fragment-read offset within a 1KB subtile
  int rd = ((lane & 15) << 6) | ((lane >> 4) << 4);
  rd ^= ((lane >> 3) & 1) << 5;

  const int aoffc = wm * 8192;          // wm*8 subtiles
  const int boffc = 65536 + wn * 4096;  // B ring + wn*4 subtiles

  f32x4 acc[8][4];
#pragma unroll
  for (int i = 0; i < 8; ++i)
#pragma unroll
    for (int j = 0; j < 4; ++j) acc[i][j] = (f32x4){0.f, 0.f, 0.f, 0.f};

  bf16x8 Af[4], Bf[4];

#define STAGE_HALF(srcR, ringoff, tile, ks, slot)                           \
  do {                                                                      \
    const unsigned short* s_ = (srcR) + (size_t)((tile) * 64 + (ks) * 32);  \
    char* d_ = smem + (ringoff) + ((slot) << 14) + wave * 2048;             \
    lds16(s_, d_);                                                          \
    lds16(s_ + (size_t)16 * KDIM, d_ + 1024);                               \
  } while (0)

#define READ_A(slotbase, mfbase)                                            \
  _Pragma("unroll") for (int mf = 0; mf < 4; ++mf)                          \
      Af[mf] = *(const bf16x8*)(smem + aoffc + (slotbase) +                 \
                                ((mfbase) + mf) * 1024 + rd);

#define READ_B(slotbase)                                                    \
  _Pragma("unroll") for (int nf = 0; nf < 4; ++nf)                          \
      Bf[nf] = *(const bf16x8*)(smem + boffc + (slotbase) + nf * 1024 + rd);

#define MFMA16(mrow)                                                        \
  __builtin_amdgcn_s_setprio(1);                                            \
  _Pragma("unroll") for (int mf = 0; mf < 4; ++mf)                          \
      _Pragma("unroll") for (int nf = 0; nf < 4; ++nf)                      \
          acc[(mrow) + mf][nf] = __builtin_amdgcn_mfma_f32_16x16x32_bf16(   \
              Af[mf], Bf[nf], acc[(mrow) + mf][nf], 0, 0, 0);               \
  __builtin_amdgcn_s_setprio(0);

#define BAR                                                                 \
  __builtin_amdgcn_s_barrier();                                             \
  __builtin_amdgcn_sched_barrier(0);

#define VMWAIT(N) asm volatile("s_waitcnt vmcnt(" #N ")" ::: "memory")

  // TILE: S0s/S1s = slots of this tile's ks0/ks1; SN1s = slot for (t+1,ks1);
  // (t+2,ks0) goes back into S0s (freed after p1's closing barrier).
#define TILE(T, S0s, S1s, SN1s, NSTG, VM1STMT, VM3STMT)                     \
  do {                                                                      \
    /* phase 0: ks0, mf 0-3 */                                              \
    READ_A((S0s) << 14, 0);                                                 \
    READ_B((S0s) << 14);                                                    \
    if ((NSTG) >= 1) STAGE_HALF(aR, 0, (T) + 1, 1, SN1s);                   \
    BAR; MFMA16(0); BAR;                                                    \
    /* phase 1: ks0, mf 4-7 */                                              \
    READ_A((S0s) << 14, 4);                                                 \
    if ((NSTG) >= 2) STAGE_HALF(bR, 65536, (T) + 1, 1, SN1s);               \
    VM1STMT; BAR; MFMA16(4); BAR;                                           \
    /* phase 2: ks1, mf 0-3 */                                              \
    READ_A((S1s) << 14, 0);                                                 \
    READ_B((S1s) << 14);                                                    \
    if ((NSTG) >= 3) STAGE_HALF(aR, 0, (T) + 2, 0, S0s);                    \
    BAR; MFMA16(0); BAR;                                                    \
    /* phase 3: ks1, mf 4-7 */                                              \
    READ_A((S1s) << 14, 4);                                                 \
    if ((NSTG) >= 4) STAGE_HALF(bR, 65536, (T) + 2, 0, S0s);                \
    VM3STMT; BAR; MFMA16(4); BAR;                                           \
  } while (0)

  // prologue: A0(0),B0(0),A1(0),B1(0),A0(1),B0(1) = 12 loads; wait first 4
  STAGE_HALF(aR, 0, 0, 0, 0);
  STAGE_HALF(bR, 65536, 0, 0, 0);
  STAGE_HALF(aR, 0, 0, 1, 1);
  STAGE_HALF(bR, 65536, 0, 1, 1);
  STAGE_HALF(aR, 0, 1, 0, 2);
  STAGE_HALF(bR, 65536, 1, 0, 2);
  VMWAIT(8);
  BAR;

  for (int tt = 0; tt < 62; tt += 2) {
    TILE(tt,     0, 1, 3, 4, VMWAIT(8), VMWAIT(8));
    TILE(tt + 1, 2, 3, 1, 4, VMWAIT(8), VMWAIT(8));
  }
  // t=62: stage only A1(63),B1(63); t=63: no staging, drain
  TILE(62, 0, 1, 3, 2, VMWAIT(8), VMWAIT(4));
  TILE(63, 2, 3, 1, 0, VMWAIT(0), (void)0);

#undef TILE
#undef VMWAIT
#undef BAR
#undef MFMA16
#undef READ_B
#undef READ_A
#undef STAGE_HALF

  // epilogue: C/D layout col=lane&15 (n), row=(lane>>4)*4+reg (m)
  const int colbase = bn0 + wn * 64 + (lane & 15);
  const int rowbase = bm0 + wm * 128 + ((lane >> 4) << 2);
  float bv[4];
#pragma unroll
  for (int nf = 0; nf < 4; ++nf) bv[nf] = bias[colbase + nf * 16];
#pragma unroll
  for (int mf = 0; mf < 8; ++mf)
#pragma unroll
    for (int nf = 0; nf < 4; ++nf) {
      size_t base = (size_t)(rowbase + mf * 16) * NDIM + colbase + nf * 16;
#pragma unroll
      for (int r = 0; r < 4; ++r)
        out[base + (size_t)r * NDIM] = acc[mf][nf][r] + bv[nf];
    }
}

// ---------------- fallback fused 128x128 kernel (ws too small) --------------
__global__ __launch_bounds__(256, 3) void gemm_fused_kernel(
    const float* __restrict__ x, const uint32_t* __restrict__ wq,
    const float* __restrict__ scales, const float* __restrict__ zeros,
    const float* __restrict__ bias, float* __restrict__ out) {
  __shared__ __align__(16) char smem[2 * 128 * 64 * 2];
  char* As = smem;
  char* Bs = smem + 16384;

  const int tid  = threadIdx.x;
  const int lane = tid & 63;
  const int wave = tid >> 6;
  const int wm = wave >> 1, wn = wave & 1;

  const int b   = blockIdx.x;
  const int swz = (b & 7) * 344 + (b >> 3);
  const int mt  = swz / 86;
  const int nt  = swz - mt * 86;
  const int bm0 = mt * 128, bn0 = nt * 128;

  f32x4 acc[4][4];
#pragma unroll
  for (int i = 0; i < 4; ++i)
#pragma unroll
    for (int j = 0; j < 4; ++j) acc[i][j] = (f32x4){0.f, 0.f, 0.f, 0.f};

  const int base_a = ((wm * 64 + (lane & 15)) << 7) + ((lane >> 4) << 4);
  const int base_b = ((wn * 64 + (lane & 15)) << 7) + ((lane >> 4) << 4);

  float sv[4], zv[4];
#pragma unroll
  for (int it = 0; it < 4; ++it) {
    int r = bn0 + it * 32 + (tid >> 3);
    sv[it] = bf16r(scales[r]);
    zv[it] = bf16r(zeros[r]);
  }

  for (int kt = 0; kt < KDIM / 64; ++kt) {
    const int k0 = kt * 64;
    __syncthreads();
#pragma unroll
    for (int it = 0; it < 4; ++it) {
      int ch = it * 256 + tid;
      int row = ch >> 3, c8 = ch & 7;
      const float* src = x + (size_t)(bm0 + row) * KDIM + k0 + c8 * 8;
      float4 f0 = *(const float4*)src;
      float4 f1 = *(const float4*)(src + 4);
      u16x8 v;
      v[0] = f2bf(f0.x); v[1] = f2bf(f0.y); v[2] = f2bf(f0.z); v[3] = f2bf(f0.w);
      v[4] = f2bf(f1.x); v[5] = f2bf(f1.y); v[6] = f2bf(f1.z); v[7] = f2bf(f1.w);
      *(u16x8*)(As + row * 128 + c8 * 16) = v;
    }
#pragma unroll
    for (int it = 0; it < 4; ++it) {
      int ch = it * 256 + tid;
      int row = ch >> 3, kp = ch & 7;
      uint32_t w = wq[(size_t)(bn0 + row) * KP + kt * 8 + kp];
      float s = sv[it], z = zv[it];
      u16x8 v;
#pragma unroll
      for (int j = 0; j < 8; ++j) {
        float qf = (float)((w >> (4 * j)) & 0xF);
        float t  = bf16r(qf * s);
        v[j] = f2bf(t + z);
      }
      *(u16x8*)(Bs + row * 128 + kp * 16) = v;
    }
    __syncthreads();
#pragma unroll
    for (int ks = 0; ks < 2; ++ks) {
      bf16x8 af[4], bf[4];
#pragma unroll
      for (int i = 0; i < 4; ++i)
        af[i] = *(const bf16x8*)(As + base_a + i * 2048 + ks * 64);
#pragma unroll
      for (int j = 0; j < 4; ++j)
        bf[j] = *(const bf16x8*)(Bs + base_b + j * 2048 + ks * 64);
#pragma unroll
      for (int i = 0; i < 4; ++i)
#pragma unroll
        for (int j = 0; j < 4; ++j)
          acc[i][j] = __builtin_amdgcn_mfma_f32_16x16x32_bf16(af[i], bf[j],
                                                              acc[i][j], 0, 0, 0);
    }
  }

  const int colbase = bn0 + wn * 64 + (lane & 15);
  const int rowbase = bm0 + wm * 64 + ((lane >> 4) << 2);
  float bv[4];
#pragma unroll
  for (int j = 0; j < 4; ++j) bv[j] = bias[colbase + j * 16];
#pragma unroll
  for (int i = 0; i < 4; ++i) {
#pragma unroll
    for (int j = 0; j < 4; ++j) {
      size_t base = (size_t)(rowbase + i * 16) * NDIM + colbase + j * 16;
#pragma unroll
      for (int r = 0; r < 4; ++r)
        out[base + (size_t)r * NDIM] = acc[i][j][r] + bv[j];
    }
  }
}

extern "C" void kernel_launch(void* const* d_in, const int* in_sizes, int n_in,
                              void* d_out, int out_size, void* d_ws, size_t ws_size,
                              hipStream_t stream) {
  const float*    x      = (const float*)d_in[0];
  const uint32_t* wq     = (const uint32_t*)d_in[1];
  const float*    scales = (const float*)d_in[2];
  const float*    zeros  = (const float*)d_in[3];
  const float*    bias   = (const float*)d_in[4];
  float*          out    = (float*)d_out;

  const size_t needW = (size_t)NDIM * KDIM * 2;  // 90,177,536 B
  const size_t needX = (size_t)MDIM * KDIM * 2;  // 33,554,432 B

  if (ws_size >= needW + needX) {
    unsigned short* Wbf = (unsigned short*)d_ws;
    unsigned short* Xbf = (unsigned short*)((char*)d_ws + needW);
    dequant_w_kernel<<<(NDIM * KP) / 256, 256, 0, stream>>>(wq, scales, zeros,
                                                            (u16x8*)Wbf);
    convert_x_kernel<<<(MDIM * KDIM / 8) / 256, 256, 0, stream>>>(
        (const float4*)x, (u16x8*)Xbf);
    gemm256_kernel<<<688, 512, 0, stream>>>(Xbf, Wbf, bias, out);
  } else {
    gemm_fused_kernel<<<2752, 256, 0, stream>>>(x, wq, scales, zeros, bias, out);
  }
}